// Round 1
// baseline (114.354 us; speedup 1.0000x reference)
//
#include <hip/hip_runtime.h>

#define TOPK 20
#define NITEMS 50000
#define BLOCK 1024
#define NWAVES (BLOCK / 64)

// SmoothRank NDCG.
// rank_j = sum_i sigmoid(s_i - t_j) + 0.5 = sum_i 1/(1 + exp(t_j)*exp(-s_i)) + 0.5
// Key restructure: exp(-s_i) once per element; per-j cost = fma + rcp only.
__global__ __launch_bounds__(BLOCK) void smoothdcg_kernel(
    const float* __restrict__ scores_top,  // [B][TOPK]
    const float* __restrict__ scores,      // [B][NITEMS]
    const float* __restrict__ labels,      // [B][TOPK]
    float* __restrict__ out)               // [B][TOPK]
{
    const int b   = blockIdx.x;
    const int tid = threadIdx.x;

    __shared__ float s_c[TOPK];
    __shared__ float s_partial[NWAVES][TOPK];

    if (tid < TOPK) {
        s_c[tid] = __expf(scores_top[b * TOPK + tid]);  // c_j = exp(t_j), TEMP=1
    }
    __syncthreads();

    float c[TOPK];
#pragma unroll
    for (int j = 0; j < TOPK; ++j) c[j] = s_c[j];

    float acc[TOPK];
#pragma unroll
    for (int j = 0; j < TOPK; ++j) acc[j] = 0.0f;

    const float4* row = (const float4*)(scores + (size_t)b * NITEMS);
    const int n4 = NITEMS / 4;  // 12500

    for (int i = tid; i < n4; i += BLOCK) {
        float4 v = row[i];
        float e0 = __expf(-v.x);
        float e1 = __expf(-v.y);
        float e2 = __expf(-v.z);
        float e3 = __expf(-v.w);
#pragma unroll
        for (int j = 0; j < TOPK; ++j) {
            acc[j] += __builtin_amdgcn_rcpf(fmaf(c[j], e0, 1.0f));
            acc[j] += __builtin_amdgcn_rcpf(fmaf(c[j], e1, 1.0f));
            acc[j] += __builtin_amdgcn_rcpf(fmaf(c[j], e2, 1.0f));
            acc[j] += __builtin_amdgcn_rcpf(fmaf(c[j], e3, 1.0f));
        }
    }

    // wave-level butterfly reduction (64 lanes)
#pragma unroll
    for (int j = 0; j < TOPK; ++j) {
        float v = acc[j];
#pragma unroll
        for (int off = 32; off >= 1; off >>= 1)
            v += __shfl_down(v, off, 64);
        acc[j] = v;
    }

    const int wave = tid >> 6;
    const int lane = tid & 63;
    if (lane == 0) {
#pragma unroll
        for (int j = 0; j < TOPK; ++j) s_partial[wave][j] = acc[j];
    }
    __syncthreads();

    if (tid == 0) {
        float rank[TOPK];
        for (int j = 0; j < TOPK; ++j) {
            float s = 0.0f;
            for (int w = 0; w < NWAVES; ++w) s += s_partial[w][j];
            rank[j] = s + 0.5f;
        }
        // idcg[k-1] = cumsum 1/log2(i+2)
        float idcg[TOPK];
        float run = 0.0f;
        for (int i = 0; i < TOPK; ++i) {
            run += 1.0f / log2f((float)i + 2.0f);
            idcg[i] = run;
        }
        float lab[TOPK];
        int ksum = 0;
        for (int j = 0; j < TOPK; ++j) {
            lab[j] = labels[b * TOPK + j];
            ksum += (int)(lab[j] + 0.5f);
        }
        float dcg = 0.0f;
        for (int j = 0; j < TOPK; ++j) {
            float d = log2f(rank[j] + 1.0f);
            dcg += lab[j] / d;
            int kc  = (ksum < (j + 1)) ? ksum : (j + 1);
            int idx = kc - 1;
            if (idx < 0) idx += TOPK;  // JAX negative-index wrap (k_sum==0 case)
            out[b * TOPK + j] = dcg / idcg[idx];
        }
    }
}

extern "C" void kernel_launch(void* const* d_in, const int* in_sizes, int n_in,
                              void* d_out, int out_size, void* d_ws, size_t ws_size,
                              hipStream_t stream) {
    const float* scores_top = (const float*)d_in[0];
    const float* scores     = (const float*)d_in[1];
    const float* labels     = (const float*)d_in[2];
    float* out              = (float*)d_out;

    const int B = in_sizes[0] / TOPK;  // 256
    smoothdcg_kernel<<<dim3(B), dim3(BLOCK), 0, stream>>>(scores_top, scores, labels, out);
}

// Round 2
// 105.166 us; speedup vs baseline: 1.0874x; 1.0874x over previous
//
#include <hip/hip_runtime.h>

#define TOPK 20
#define NITEMS 50000
#define BLOCK 1024
#define NWAVES (BLOCK / 64)

__device__ __forceinline__ float readfirstlane_f32(float x) {
    return __int_as_float(__builtin_amdgcn_readfirstlane(__float_as_int(x)));
}

// SmoothRank NDCG.
// rank_j = sum_i sigmoid(s_i - t_j) + 0.5 = sum_i 1/(1 + c_j * e_i) + 0.5
//   with c_j = exp(t_j) (block-uniform, pinned to SGPRs), e_i = exp(-s_i).
// 4-way rcp fusion (exact): 1/A+1/B+1/C+1/D = (S1*P2 + S2*P1) / (P1*P2)
//   where S1=A+B, P1=A*B, S2=C+D, P2=C*D.  20 rcp/iter instead of 80.
__global__ __launch_bounds__(BLOCK) void smoothdcg_kernel(
    const float* __restrict__ scores_top,  // [B][TOPK]
    const float* __restrict__ scores,      // [B][NITEMS]
    const float* __restrict__ labels,      // [B][TOPK]
    float* __restrict__ out)               // [B][TOPK]
{
    const int b   = blockIdx.x;
    const int tid = threadIdx.x;

    __shared__ float s_partial[NWAVES][TOPK];

    // c_j = exp(t_j): uniform address -> scalar loads; pin result to SGPRs so
    // the inner-loop fma reads an SGPR operand (no LDS, no VGPR cost).
    float c[TOPK];
#pragma unroll
    for (int j = 0; j < TOPK; ++j)
        c[j] = readfirstlane_f32(__expf(scores_top[b * TOPK + j]));

    float acc[TOPK];
#pragma unroll
    for (int j = 0; j < TOPK; ++j) acc[j] = 0.0f;

    const float4* row = (const float4*)(scores + (size_t)b * NITEMS);
    const int n4 = NITEMS / 4;  // 12500

    for (int i = tid; i < n4; i += BLOCK) {
        float4 v = row[i];
        float e0 = __expf(-v.x);
        float e1 = __expf(-v.y);
        float e2 = __expf(-v.z);
        float e3 = __expf(-v.w);
#pragma unroll
        for (int j = 0; j < TOPK; ++j) {
            float A = fmaf(c[j], e0, 1.0f);
            float B = fmaf(c[j], e1, 1.0f);
            float C = fmaf(c[j], e2, 1.0f);
            float D = fmaf(c[j], e3, 1.0f);
            float P1 = A * B;
            float P2 = C * D;
            float S1 = A + B;
            float S2 = C + D;
            float num = fmaf(S1, P2, S2 * P1);
            float den = P1 * P2;
            acc[j] = fmaf(num, __builtin_amdgcn_rcpf(den), acc[j]);
        }
    }

    // wave-level butterfly reduction (64 lanes)
#pragma unroll
    for (int j = 0; j < TOPK; ++j) {
        float v = acc[j];
#pragma unroll
        for (int off = 32; off >= 1; off >>= 1)
            v += __shfl_down(v, off, 64);
        acc[j] = v;
    }

    const int wave = tid >> 6;
    const int lane = tid & 63;
    if (lane == 0) {
#pragma unroll
        for (int j = 0; j < TOPK; ++j) s_partial[wave][j] = acc[j];
    }
    __syncthreads();

    if (tid == 0) {
        float rank[TOPK];
        for (int j = 0; j < TOPK; ++j) {
            float s = 0.0f;
            for (int w = 0; w < NWAVES; ++w) s += s_partial[w][j];
            rank[j] = s + 0.5f;
        }
        // idcg[k-1] = cumsum 1/log2(i+2)
        float idcg[TOPK];
        float run = 0.0f;
        for (int i = 0; i < TOPK; ++i) {
            run += 1.0f / log2f((float)i + 2.0f);
            idcg[i] = run;
        }
        float lab[TOPK];
        int ksum = 0;
        for (int j = 0; j < TOPK; ++j) {
            lab[j] = labels[b * TOPK + j];
            ksum += (int)(lab[j] + 0.5f);
        }
        float dcg = 0.0f;
        for (int j = 0; j < TOPK; ++j) {
            float d = log2f(rank[j] + 1.0f);
            dcg += lab[j] / d;
            int kc  = (ksum < (j + 1)) ? ksum : (j + 1);
            int idx = kc - 1;
            if (idx < 0) idx += TOPK;  // JAX negative-index wrap (k_sum==0 case)
            out[b * TOPK + j] = dcg / idcg[idx];
        }
    }
}

extern "C" void kernel_launch(void* const* d_in, const int* in_sizes, int n_in,
                              void* d_out, int out_size, void* d_ws, size_t ws_size,
                              hipStream_t stream) {
    const float* scores_top = (const float*)d_in[0];
    const float* scores     = (const float*)d_in[1];
    const float* labels     = (const float*)d_in[2];
    float* out              = (float*)d_out;

    const int B = in_sizes[0] / TOPK;  // 256
    smoothdcg_kernel<<<dim3(B), dim3(BLOCK), 0, stream>>>(scores_top, scores, labels, out);
}

// Round 3
// 104.141 us; speedup vs baseline: 1.0981x; 1.0098x over previous
//
#include <hip/hip_runtime.h>

#define TOPK 20
#define NITEMS 50000
#define BLOCK 1024
#define NWAVES (BLOCK / 64)
#define SPLIT 2
#define HALF_N (NITEMS / SPLIT)   // 25000
#define NH4 (HALF_N / 4)          // 6250

__device__ __forceinline__ float readfirstlane_f32(float x) {
    return __int_as_float(__builtin_amdgcn_readfirstlane(__float_as_int(x)));
}

// SmoothRank NDCG, symmetric-polynomial form.
// For a group of 4 elements with e_k = exp(-s_k) and c_j = exp(t_j):
//   sum_k sigmoid(s_k - t_j) = sum_k 1/(1 + c_j*e_k) = num(c_j)/den(c_j)
//   den(c) = prod(1+c*e_k) = 1 + E1 c + E2 c^2 + E3 c^3 + E4 c^4
//   num(c) = 4 + 3E1 c + 2E2 c^2 + E3 c^3
// E1..E4 (elementary symmetric polys) are computed ONCE per group and shared
// across all 20 j.  c_j, c_j^2 live in SGPRs (block-uniform).  Per-j cost:
// 7 fma + 1 rcp + 1 acc-fma.  All terms positive -> no cancellation.
__global__ __launch_bounds__(BLOCK, 8) void partial_kernel(
    const float* __restrict__ scores_top,  // [B][TOPK]
    const float* __restrict__ scores,      // [B][NITEMS]
    float* __restrict__ partials)          // [B*SPLIT][TOPK]
{
    const int bid  = blockIdx.x;
    const int row  = bid >> 1;
    const int half = bid & 1;
    const int tid  = threadIdx.x;

    __shared__ float s_partial[NWAVES][TOPK];

    float c[TOPK], c2[TOPK];
#pragma unroll
    for (int j = 0; j < TOPK; ++j) {
        float cj = readfirstlane_f32(__expf(scores_top[row * TOPK + j]));
        c[j]  = cj;
        c2[j] = readfirstlane_f32(cj * cj);
    }

    float acc[TOPK];
#pragma unroll
    for (int j = 0; j < TOPK; ++j) acc[j] = 0.0f;

    const float4* rp = (const float4*)(scores + (size_t)row * NITEMS + (size_t)half * HALF_N);

    float4 v = make_float4(0.f, 0.f, 0.f, 0.f);
    if (tid < NH4) v = rp[tid];

    for (int i = tid; i < NH4; i += BLOCK) {
        // prefetch next iteration's data before the heavy compute
        const int inext = i + BLOCK;
        float4 vn = v;
        if (inext < NH4) vn = rp[inext];

        float e0 = __expf(-v.x);
        float e1 = __expf(-v.y);
        float e2 = __expf(-v.z);
        float e3 = __expf(-v.w);

        float s01 = e0 + e1, s23 = e2 + e3;
        float p01 = e0 * e1, p23 = e2 * e3;
        float E1 = s01 + s23;
        float E2 = fmaf(s01, s23, p01 + p23);
        float E3 = fmaf(p01, s23, p23 * s01);
        float E4 = p01 * p23;
        float F1 = 3.0f * E1;
        float F2 = E2 + E2;

#pragma unroll
        for (int j = 0; j < TOPK; ++j) {
            float n1  = fmaf(E3, c[j], F2);
            float n2  = fmaf(F1, c[j], 4.0f);
            float num = fmaf(c2[j], n1, n2);
            float d1  = fmaf(E4, c[j], E3);
            float d2  = fmaf(d1, c[j], E2);
            float d3  = fmaf(E1, c[j], 1.0f);
            float den = fmaf(c2[j], d2, d3);
            acc[j] = fmaf(num, __builtin_amdgcn_rcpf(den), acc[j]);
        }
        v = vn;
    }

    // wave-level butterfly reduction (64 lanes)
#pragma unroll
    for (int j = 0; j < TOPK; ++j) {
        float r = acc[j];
#pragma unroll
        for (int off = 32; off >= 1; off >>= 1)
            r += __shfl_down(r, off, 64);
        acc[j] = r;
    }

    const int wave = tid >> 6;
    const int lane = tid & 63;
    if (lane == 0) {
#pragma unroll
        for (int j = 0; j < TOPK; ++j) s_partial[wave][j] = acc[j];
    }
    __syncthreads();

    if (tid < TOPK) {
        float s = 0.0f;
#pragma unroll
        for (int w = 0; w < NWAVES; ++w) s += s_partial[w][tid];
        partials[bid * TOPK + tid] = s;
    }
}

__global__ __launch_bounds__(64) void finalize_kernel(
    const float* __restrict__ partials,  // [B*SPLIT][TOPK]
    const float* __restrict__ labels,    // [B][TOPK]
    float* __restrict__ out)             // [B][TOPK]
{
    const int b   = blockIdx.x;
    const int tid = threadIdx.x;

    __shared__ float s_rank[TOPK];
    if (tid < TOPK) {
        s_rank[tid] = partials[(2 * b) * TOPK + tid]
                    + partials[(2 * b + 1) * TOPK + tid] + 0.5f;
    }
    __syncthreads();

    if (tid == 0) {
        // idcg[k-1] = cumsum 1/log2(i+2)
        float idcg[TOPK];
        float run = 0.0f;
        for (int i = 0; i < TOPK; ++i) {
            run += 1.0f / log2f((float)i + 2.0f);
            idcg[i] = run;
        }
        float lab[TOPK];
        int ksum = 0;
        for (int j = 0; j < TOPK; ++j) {
            lab[j] = labels[b * TOPK + j];
            ksum += (int)(lab[j] + 0.5f);
        }
        float dcg = 0.0f;
        for (int j = 0; j < TOPK; ++j) {
            float d = log2f(s_rank[j] + 1.0f);
            dcg += lab[j] / d;
            int kc  = (ksum < (j + 1)) ? ksum : (j + 1);
            int idx = kc - 1;
            if (idx < 0) idx += TOPK;  // JAX negative-index wrap (k_sum==0 case)
            out[b * TOPK + j] = dcg / idcg[idx];
        }
    }
}

extern "C" void kernel_launch(void* const* d_in, const int* in_sizes, int n_in,
                              void* d_out, int out_size, void* d_ws, size_t ws_size,
                              hipStream_t stream) {
    const float* scores_top = (const float*)d_in[0];
    const float* scores     = (const float*)d_in[1];
    const float* labels     = (const float*)d_in[2];
    float* out              = (float*)d_out;
    float* partials         = (float*)d_ws;   // B*SPLIT*TOPK floats = 40 KB

    const int B = in_sizes[0] / TOPK;  // 256
    partial_kernel<<<dim3(B * SPLIT), dim3(BLOCK), 0, stream>>>(scores_top, scores, partials);
    finalize_kernel<<<dim3(B), dim3(64), 0, stream>>>(partials, labels, out);
}